// Round 1
// baseline (400.182 us; speedup 1.0000x reference)
//
#include <hip/hip_runtime.h>
#include <hip/hip_bf16.h>
#include <math.h>

// MultiEmbodimentActionEncoder: B=64,T=64,A=64,H=1024,C=16
// out = (swish(concat(act@W1[c]+b1, tau) @ W2[c] + b2)) @ W3[c] + b3
//
// Strategy R0: bf16 MFMA (16x16x32) everywhere; weights converted
// fp32->bf16 in-register during B-fragment assembly (no LDS, no transpose).
// ws layout: x = (64*64, 2048) bf16 ; h = (64*64, 1024) bf16.

typedef short bf16x8 __attribute__((ext_vector_type(8)));
typedef float floatx4 __attribute__((ext_vector_type(4)));

__device__ inline short f2bf(float f) {
  union { float f; unsigned u; } v; v.f = f;
  unsigned u = v.u;
  unsigned r = (u + 0x7fffu + ((u >> 16) & 1u)) >> 16;   // RTNE
  return (short)(r & 0xffffu);
}

// One block = 256 threads = 4 waves; block handles (batch b, 128-col strip).
// Wave w owns 32 cols. acc = 4 m-tiles x 2 n-tiles of 16x16.
// A-frag: lane holds A[m=l16][k=quad*8+j] (contiguous 16B). B-frag: lane holds
// W[k=quad*8+j][n=l16] (8 strided fp32 loads -> cvt bf16).
template<int K, bool A_F32, bool SWISH, bool OUT_BF16>
__global__ __launch_bounds__(256) void gemm_kernel(
    const void* __restrict__ Aall, int lda,
    const float* __restrict__ Wall,   // (16, K, 1024)
    const float* __restrict__ bias,   // (16, 1024)
    const int* __restrict__ cat_ids,
    void* __restrict__ Out, int ldo)
{
  constexpr int N = 1024;
  const int b    = blockIdx.y;
  const int c    = cat_ids[b];
  const int tid  = threadIdx.x;
  const int wave = tid >> 6;
  const int lane = tid & 63;
  const int quad = lane >> 4;
  const int l16  = lane & 15;
  const int n_wave = blockIdx.x * 128 + wave * 32;

  const float* W  = Wall + (size_t)c * K * N;
  const float* bs = bias + (size_t)c * N;

  floatx4 acc[4][2];
  #pragma unroll
  for (int mt = 0; mt < 4; ++mt)
    #pragma unroll
    for (int nt = 0; nt < 2; ++nt)
      acc[mt][nt] = (floatx4){0.f, 0.f, 0.f, 0.f};

  const float* Af = (const float*)Aall + (size_t)(b * 64) * lda;
  const short* Ab = (const short*)Aall + (size_t)(b * 64) * lda;

  #pragma unroll 2
  for (int k0 = 0; k0 < K; k0 += 32) {
    const int kk = k0 + quad * 8;

    bf16x8 af[4];
    #pragma unroll
    for (int mt = 0; mt < 4; ++mt) {
      const int row = mt * 16 + l16;
      if constexpr (A_F32) {
        const floatx4* p = (const floatx4*)(Af + (size_t)row * lda + kk);
        floatx4 x0 = p[0];
        floatx4 x1 = p[1];
        bf16x8 t;
        t[0] = f2bf(x0[0]); t[1] = f2bf(x0[1]); t[2] = f2bf(x0[2]); t[3] = f2bf(x0[3]);
        t[4] = f2bf(x1[0]); t[5] = f2bf(x1[1]); t[6] = f2bf(x1[2]); t[7] = f2bf(x1[3]);
        af[mt] = t;
      } else {
        af[mt] = *(const bf16x8*)(Ab + (size_t)row * lda + kk);
      }
    }

    bf16x8 bfr[2];
    #pragma unroll
    for (int nt = 0; nt < 2; ++nt) {
      const int n = n_wave + nt * 16 + l16;
      const float* wp = W + (size_t)kk * N + n;
      bf16x8 t;
      #pragma unroll
      for (int j = 0; j < 8; ++j) t[j] = f2bf(wp[(size_t)j * N]);
      bfr[nt] = t;
    }

    #pragma unroll
    for (int nt = 0; nt < 2; ++nt)
      #pragma unroll
      for (int mt = 0; mt < 4; ++mt)
        acc[mt][nt] = __builtin_amdgcn_mfma_f32_16x16x32_bf16(af[mt], bfr[nt], acc[mt][nt], 0, 0, 0);
  }

  // Epilogue: C/D layout row = mt*16 + quad*4 + r, col = n_wave + nt*16 + l16
  #pragma unroll
  for (int nt = 0; nt < 2; ++nt) {
    const int n = n_wave + nt * 16 + l16;
    const float bv = bs[n];
    #pragma unroll
    for (int mt = 0; mt < 4; ++mt) {
      #pragma unroll
      for (int r = 0; r < 4; ++r) {
        const int row = mt * 16 + quad * 4 + r;
        float v = acc[mt][nt][r] + bv;
        if constexpr (SWISH) v = v / (1.f + __expf(-v));
        if constexpr (OUT_BF16)
          ((short*)Out)[(size_t)(b * 64 + row) * ldo + n] = f2bf(v);
        else
          ((float*)Out)[(size_t)(b * 64 + row) * ldo + n] = v;
      }
    }
  }
}

// tau: per batch, one 1024-vector (timestep constant across T), broadcast to
// 64 rows of x's right half. x row stride 2048 bf16.
__global__ __launch_bounds__(256) void tau_kernel(const int* __restrict__ ts,
                                                  short* __restrict__ x)
{
  const int b = blockIdx.x;
  const float t = (float)ts[b];
  const int tid = threadIdx.x;
  #pragma unroll
  for (int q = 0; q < 4; ++q) {
    const int i  = q * 256 + tid;          // [0,1024)
    const int hi = i & 511;
    // ln(10000)/512
    const float e = __expf(-(float)hi * 0.017988946039015980f);
    const float freq = t * e;
    const float v = (i < 512) ? sinf(freq) : cosf(freq);
    const short sv = f2bf(v);
    short* base = x + (size_t)(b * 64) * 2048 + 1024 + i;
    #pragma unroll 4
    for (int tt = 0; tt < 64; ++tt) base[(size_t)tt * 2048] = sv;
  }
}

extern "C" void kernel_launch(void* const* d_in, const int* in_sizes, int n_in,
                              void* d_out, int out_size, void* d_ws, size_t ws_size,
                              hipStream_t stream) {
  const float* actions   = (const float*)d_in[0];
  const int*   timesteps = (const int*)  d_in[1];
  const int*   cat_ids   = (const int*)  d_in[2];
  const float* W1 = (const float*)d_in[3];
  const float* b1 = (const float*)d_in[4];
  const float* W2 = (const float*)d_in[5];
  const float* b2 = (const float*)d_in[6];
  const float* W3 = (const float*)d_in[7];
  const float* b3 = (const float*)d_in[8];

  short* x = (short*)d_ws;                       // (4096, 2048) bf16 = 16 MiB
  short* h = x + (size_t)64 * 64 * 2048;         // (4096, 1024) bf16 =  8 MiB

  dim3 grid(8, 64), blk(256);

  // GEMM1: a_emb = actions @ W1[c] + b1[c] -> x[:, 0:1024]
  gemm_kernel<64, true, false, true><<<grid, blk, 0, stream>>>(
      (const void*)actions, 64, W1, b1, cat_ids, (void*)x, 2048);

  // tau -> x[:, 1024:2048]
  tau_kernel<<<64, 256, 0, stream>>>(timesteps, x);

  // GEMM2 + swish: h = swish(x @ W2[c] + b2[c])
  gemm_kernel<2048, false, true, true><<<grid, blk, 0, stream>>>(
      (const void*)x, 2048, W2, b2, cat_ids, (void*)h, 1024);

  // GEMM3: out = h @ W3[c] + b3[c]  (fp32)
  gemm_kernel<1024, false, false, false><<<grid, blk, 0, stream>>>(
      (const void*)h, 1024, W3, b3, cat_ids, d_out, 1024);
}